// Round 5
// baseline (127.938 us; speedup 1.0000x reference)
//
#include <hip/hip_runtime.h>
#include <cstdint>
#include <cstddef>

#define NB 8
#define NS 2048
#define ND 768
#define NSP 512
#define MAXW 30
#define NH 100
#define LDP 104        // P row stride in floats (26 float4)
#define NKS (ND / 32)  // 24 k-steps of 32

typedef __attribute__((ext_vector_type(8))) short short8;
typedef __attribute__((ext_vector_type(4))) float floatx4;

union U4S8 { uint4 v; short8 s8; unsigned u[4]; unsigned short us[8]; };

// float -> bf16 RNE (used only in pack_b, off the hot path)
__device__ inline unsigned short f2bf(float f) {
    unsigned u = __float_as_uint(f);
    return (unsigned short)((u + 0x7fffu + ((u >> 16) & 1u)) >> 16);
}

// truncate-split of a float pair into packed bf16x2 hi and lo.
// hi = top 16 bits (truncation); lo = truncation of exact residual.
// |err| <= 2^-16 rel — negligible vs the B operand's 2^-9.
__device__ inline void split2(float x0, float x1, unsigned& hi, unsigned& lo) {
    unsigned u0 = __float_as_uint(x0), u1 = __float_as_uint(x1);
    unsigned h0 = u0 & 0xFFFF0000u, h1 = u1 & 0xFFFF0000u;
    hi = (u0 >> 16) | h1;
    float r0 = x0 - __uint_as_float(h0);
    float r1 = x1 - __uint_as_float(h1);
    lo = (__float_as_uint(r0) >> 16) | (__float_as_uint(r1) & 0xFFFF0000u);
}

// Kernel 0: pack B = [ffnn_w | att_w | 0-pad] (768 x 128) into MFMA B-fragment order, bf16.
// Frag (ks, cf): lane l holds B[k = ks*32 + (l>>4)*8 + j][n = cf*16 + (l&15)], j=0..7.
__global__ __launch_bounds__(256) void pack_b_kernel(
    const float* __restrict__ ffnn_w, const float* __restrict__ att_w,
    uint4* __restrict__ Bfrag)
{
    int ks = blockIdx.x;
    for (int idx = threadIdx.x; idx < 8 * 64; idx += 256) {
        int cf = idx >> 6, lane = idx & 63;
        int q = lane >> 4, r = lane & 15;
        int n = cf * 16 + r;
        U4S8 p;
#pragma unroll
        for (int j = 0; j < 8; j++) {
            int k = ks * 32 + q * 8 + j;
            float v = (n < NH) ? ffnn_w[(size_t)k * NH + n]
                               : (n == NH ? att_w[k] : 0.f);
            p.us[j] = f2bf(v);
        }
        Bfrag[(size_t)(ks * 8 + cf) * 64 + lane] = p.v;
    }
}

// Kernel 1: P[row, 0..99] = seq·ffnn_w, Lg[row] = seq·att_w  via split-A bf16 MFMA.
// 1024 blocks x 4 waves (16 waves/CU); wave = 16 rows x 32 cols; no LDS.
__global__ __launch_bounds__(256, 4) void proj_kernel(
    const float* __restrict__ seq, const uint4* __restrict__ Bfrag,
    float* __restrict__ P, float* __restrict__ Lg)
{
    const int t = threadIdx.x;
    const int wave = t >> 6, lane = t & 63;
    const int q = lane >> 4, r = lane & 15;
    const int cf0 = wave * 2;              // this wave's two col-frags
    const int row0 = blockIdx.x * 16;

    floatx4 acc[2] = {{0.f, 0.f, 0.f, 0.f}, {0.f, 0.f, 0.f, 0.f}};

    const float* arow = seq + (size_t)(row0 + r) * ND + q * 8;
    const uint4* bptr = Bfrag + (size_t)cf0 * 64 + lane;

#pragma unroll 2
    for (int ks = 0; ks < NKS; ++ks) {
        float4 f0 = *(const float4*)(arow + ks * 32);
        float4 f1 = *(const float4*)(arow + ks * 32 + 4);
        U4S8 b0, b1;
        b0.v = bptr[(size_t)ks * 8 * 64];
        b1.v = bptr[(size_t)ks * 8 * 64 + 64];

        U4S8 hi, lo;
        split2(f0.x, f0.y, hi.u[0], lo.u[0]);
        split2(f0.z, f0.w, hi.u[1], lo.u[1]);
        split2(f1.x, f1.y, hi.u[2], lo.u[2]);
        split2(f1.z, f1.w, hi.u[3], lo.u[3]);

        acc[0] = __builtin_amdgcn_mfma_f32_16x16x32_bf16(hi.s8, b0.s8, acc[0], 0, 0, 0);
        acc[0] = __builtin_amdgcn_mfma_f32_16x16x32_bf16(lo.s8, b0.s8, acc[0], 0, 0, 0);
        acc[1] = __builtin_amdgcn_mfma_f32_16x16x32_bf16(hi.s8, b1.s8, acc[1], 0, 0, 0);
        acc[1] = __builtin_amdgcn_mfma_f32_16x16x32_bf16(lo.s8, b1.s8, acc[1], 0, 0, 0);
    }

    // C/D layout: col = cf*16 + r, row = row0 + q*4 + reg
#pragma unroll
    for (int c = 0; c < 2; ++c) {
        int col = (cf0 + c) * 16 + r;
        if (col < NH) {
#pragma unroll
            for (int reg = 0; reg < 4; ++reg)
                P[(size_t)(row0 + q * 4 + reg) * LDP + col] = acc[c][reg];
        } else if (col == NH) {
#pragma unroll
            for (int reg = 0; reg < 4; ++reg)
                Lg[row0 + q * 4 + reg] = acc[c][reg];
        }
    }
}

// Kernel 2: one wave per span. Softmax over Lg (coalesced; att_b cancels), then
// out[n, 4l..4l+3] = tanh(mask * sum_i attn_i * P4[st+i, l] + b4[l])  (float4 lanes).
__global__ __launch_bounds__(256) void span_kernel(
    const int* __restrict__ span_idx, const int* __restrict__ span_mask,
    const float* __restrict__ P, const float* __restrict__ Lg,
    const float* __restrict__ ffnn_b, float* __restrict__ out)
{
    const int wave = threadIdx.x >> 6, lane = threadIdx.x & 63;
    const int gs = blockIdx.x * 4 + wave;          // [0, 4096)
    const int b = gs / NSP;
    const int st = span_idx[2 * gs];
    int w = span_idx[2 * gs + 1] - st;             // width in [1, MAXW]
    w = max(1, min(w, MAXW));

    // masked softmax over span width (coalesced logit read from Lg)
    float lg = -1e30f;
    if (lane < w) lg = Lg[b * NS + st + lane];
    float mx = lg;
#pragma unroll
    for (int off = 32; off > 0; off >>= 1) mx = fmaxf(mx, __shfl_xor(mx, off));
    float e = (lane < w) ? __expf(lg - mx) : 0.f;
    float sum = e;
#pragma unroll
    for (int off = 32; off > 0; off >>= 1) sum += __shfl_xor(sum, off);
    float attn = e / sum;                          // 0 for lanes >= w

    // attended: lane l (0..24) owns h = 4l..4l+3 as a float4. Lanes 25..63
    // clamp to lane 24's address (same cache line, results discarded).
    int cl = min(lane, 24);
    const float4* Pb4 = (const float4*)(P + ((size_t)b * NS + st) * LDP) + cl;
    float4 acc = {0.f, 0.f, 0.f, 0.f};
#pragma unroll
    for (int i = 0; i < MAXW; ++i) {               // fixed trip; attn_i==0 for i>=w
        float a = __shfl(attn, i);
        float4 v = Pb4[i * (LDP / 4)];
        acc.x += a * v.x; acc.y += a * v.y; acc.z += a * v.z; acc.w += a * v.w;
    }

    if (lane < 25) {
        float m = (float)span_mask[gs];
        float4 bias = ((const float4*)ffnn_b)[lane];
        float4 o;
        o.x = tanhf(m * acc.x + bias.x);
        o.y = tanhf(m * acc.y + bias.y);
        o.z = tanhf(m * acc.z + bias.z);
        o.w = tanhf(m * acc.w + bias.w);
        *(float4*)(out + (size_t)gs * NH + 4 * lane) = o;
    }
}

extern "C" void kernel_launch(void* const* d_in, const int* in_sizes, int n_in,
                              void* d_out, int out_size, void* d_ws, size_t ws_size,
                              hipStream_t stream) {
    const float* seq      = (const float*)d_in[0];  // [B,S,D]
    const int*   span_idx = (const int*)d_in[1];    // [B,N,2] int32 on device
    const int*   span_msk = (const int*)d_in[2];    // [B,N]
    const float* att_w    = (const float*)d_in[3];  // [D,1]
    // d_in[4] = att_b: cancels inside softmax — unused
    const float* ffnn_w   = (const float*)d_in[5];  // [D,H]
    const float* ffnn_b   = (const float*)d_in[6];  // [H]
    float* out = (float*)d_out;                     // [B,N,H]

    char* ws = (char*)d_ws;
    float* P     = (float*)ws;                                   // 16384*104*4 = 6.82 MB
    uint4* Bfrag = (uint4*)(ws + (size_t)NB * NS * LDP * 4);     // 196 KB
    float* Lg    = (float*)(ws + (size_t)NB * NS * LDP * 4 + (size_t)NKS * 8 * 64 * 16);  // 64 KB

    pack_b_kernel<<<NKS, 256, 0, stream>>>(ffnn_w, att_w, Bfrag);
    proj_kernel<<<(NB * NS) / 16, 256, 0, stream>>>(seq, Bfrag, P, Lg);
    span_kernel<<<(NB * NSP) / 4, 256, 0, stream>>>(span_idx, span_msk, P, Lg, ffnn_b, out);
}